// Round 8
// baseline (290.529 us; speedup 1.0000x reference)
//
#include <hip/hip_runtime.h>
#include <hip/hip_bf16.h>

// GCNBlock: 5-dispatch pipeline (R8).
//   1 init_prep:    zero deg_cnt ; repack W -> Wb bf16
//   2 scatter_gemm: ONE edge pass builds fixed-stride CSR (atomic slot claim,
//                   scatter src into csr_fixed[dst*128+pos]) || full GEMM
//   3 aggregate:    per-row gather from csr_fixed[row*128..], dinv on the fly
//   4 finalize_stats
//   5 norm_prelu
// Fixed-stride buckets: deg ~ Poisson(16); P(deg>=128) ~ 1e-67 -> S=128 safe
// (write guarded by pos<S anyway). Replaces count+rank+build_ptr+fill (two
// edge passes + 2 index arrays) with one pass; bucket starts row*S are
// monotone/deterministic (restores R3 aggregate locality that R7 lost).
// Lessons kept: no mega-fusion (R6 spill), no 1-address f64 atomics (R4),
// returning atomics on deg_cnt spread across 50K addresses are fine (R1).
// N=50000, E=800000, F=256

#define F 256
#define SLOTS 128
#define EPSV 1e-5f

typedef __attribute__((ext_vector_type(8))) short short8;
typedef __attribute__((ext_vector_type(4))) float f32x4;

__device__ __forceinline__ unsigned short f2bf(float f) {
  union { float f; unsigned u; } v; v.f = f;
  unsigned r = v.u + 0x7fffu + ((v.u >> 16) & 1u);  // RNE
  return (unsigned short)(r >> 16);
}

__device__ __forceinline__ float bf2f(unsigned short u) {
  union { unsigned u; float f; } v; v.u = ((unsigned)u) << 16; return v.f;
}

// ---- 1: zero deg_cnt (blocks < NB) ; prep Wb (blocks >= NB) ----------------

__global__ void init_prep(int* __restrict__ deg_cnt, int N, int NB,
                          const float* __restrict__ W, unsigned short* __restrict__ Wb) {
  if ((int)blockIdx.x < NB) {
    int i = blockIdx.x * 256 + threadIdx.x;
    if (i < N) deg_cnt[i] = 0;
    return;
  }
  int gid = (blockIdx.x - NB) * 256 + threadIdx.x;  // 65536 total
  int j = gid & 7;
  int lane = (gid >> 3) & 63;
  int kc = (gid >> 9) & 7;
  int tt = gid >> 12;
  int k = kc * 32 + (lane >> 4) * 8 + j;
  int n = tt * 16 + (lane & 15);
  Wb[gid] = f2bf(W[k * 256 + n]);
}

// ---- 2: edge scatter (blocks < eb) ; gemm 64-row tiles (blocks >= eb) ------
// GEMM writes h bf16 UNSCALED (deg normalization applied in aggregate).

__global__ void scatter_gemm(const int* __restrict__ src, const int* __restrict__ dst,
                             int* __restrict__ deg_cnt, int* __restrict__ csr_fixed,
                             int E, int eb,
                             const float* __restrict__ x, const unsigned short* __restrict__ Wb,
                             ushort4* __restrict__ hb, int N) {
  // +8 pad: row stride 528B -> conflict-free ds_read_b128 fragments.
  __shared__ unsigned short A[64][264];  // 33792 B -> 4 blocks/CU

  if ((int)blockIdx.x < eb) {
    int e = blockIdx.x * 256 + threadIdx.x;
    if (e < E) {
      int d = dst[e];
      int pos = atomicAdd(&deg_cnt[d], 1);
      if (pos < SLOTS) csr_fixed[d * SLOTS + pos] = src[e];
    }
    return;
  }

  int m0 = (blockIdx.x - eb) * 64;
  int t = threadIdx.x;
  int lane = t & 63;
  int wave = t >> 6;
  int q = lane >> 4;

  // stage A: 64 rows x 256 cols fp32->bf16, coalesced
#pragma unroll
  for (int j = 0; j < 16; ++j) {
    int idx = j * 256 + t;
    int row = idx >> 6;
    int c4 = idx & 63;
    int gr = m0 + row;
    int grc = gr < N ? gr : N - 1;
    f32x4 v = __builtin_nontemporal_load((const f32x4*)(x + (size_t)grc * F + c4 * 4));
    ushort4 u;
    u.x = f2bf(v[0]); u.y = f2bf(v[1]); u.z = f2bf(v[2]); u.w = f2bf(v[3]);
    *(ushort4*)&A[row][c4 * 4] = u;
  }
  __syncthreads();

  f32x4 acc[4][4];
#pragma unroll
  for (int m = 0; m < 4; ++m)
#pragma unroll
    for (int tt = 0; tt < 4; ++tt)
      acc[m][tt] = (f32x4){0.f, 0.f, 0.f, 0.f};

  int arow = lane & 15;
  for (int kc = 0; kc < 8; ++kc) {
    short8 a[4];
#pragma unroll
    for (int m = 0; m < 4; ++m)
      a[m] = *(const short8*)&A[m * 16 + arow][kc * 32 + q * 8];
#pragma unroll
    for (int tt = 0; tt < 4; ++tt) {
      const short8 b = *(const short8*)(Wb + (((wave * 4 + tt) * 8 + kc) * 64 + lane) * 8);
#pragma unroll
      for (int m = 0; m < 4; ++m)
        acc[m][tt] = __builtin_amdgcn_mfma_f32_16x16x32_bf16(a[m], b, acc[m][tt], 0, 0, 0);
    }
  }
  __syncthreads();

  // epilogue: bf16 repack via LDS, coalesced store (h UNSCALED)
  int ccol = lane & 15;
#pragma unroll
  for (int m = 0; m < 4; ++m) {
#pragma unroll
    for (int rr = 0; rr < 4; ++rr) {
      int lrow = m * 16 + q * 4 + rr;
#pragma unroll
      for (int tt = 0; tt < 4; ++tt)
        A[lrow][(wave * 4 + tt) * 16 + ccol] = f2bf(acc[m][tt][rr]);
    }
  }
  __syncthreads();
#pragma unroll
  for (int j = 0; j < 16; ++j) {
    int idx = j * 256 + t;
    int row = idx >> 6;
    int c4 = idx & 63;
    int grow = m0 + row;
    if (grow < N) hb[(size_t)grow * 64 + c4] = *(const ushort4*)&A[row][c4 * 4];
  }
}

// ---- 3: aggregate (one row per wave, 16-way unrolled bf16 gather) ----------
// hb UNSCALED; bucket at csr_fixed[row*SLOTS..+deg); w = rsqrt(deg[src]+1)
// computed on the fly (gathers deg_cnt instead of a dinv array).

__global__ void aggregate(const ushort4* __restrict__ hb, const int* __restrict__ deg_cnt,
                          const int* __restrict__ csr_fixed, const float* __restrict__ conv_bias,
                          float* __restrict__ out, double2* __restrict__ partials, int N) {
  int wave = threadIdx.x >> 6;
  int lane = threadIdx.x & 63;
  int row = blockIdx.x * 4 + wave;
  float s1 = 0.f, s2 = 0.f;

  if (row < N) {
    int dg = deg_cnt[row];
    if (dg > SLOTS) dg = SLOTS;
    float di = rsqrtf((float)(dg + 1));  // +1 self loop
    int b0 = row * SLOTS;
    int b1 = b0 + dg;
    ushort4 self = hb[(size_t)row * 64 + lane];
    f32x4 acc;
    acc[0] = bf2f(self.x) * di; acc[1] = bf2f(self.y) * di;
    acc[2] = bf2f(self.z) * di; acc[3] = bf2f(self.w) * di;

    for (int e = b0; e < b1; e += 16) {
      int idx[16];
#pragma unroll
      for (int j = 0; j < 16; ++j) {
        int ee = e + j;
        idx[j] = csr_fixed[ee < b1 ? ee : b1 - 1];
      }
      ushort4 v[16];
#pragma unroll
      for (int j = 0; j < 16; ++j) v[j] = hb[(size_t)idx[j] * 64 + lane];
      float w[16];
#pragma unroll
      for (int j = 0; j < 16; ++j) {
        int dc = deg_cnt[idx[j]];
        w[j] = rsqrtf((float)(dc + 1));
      }
#pragma unroll
      for (int j = 0; j < 16; ++j) {
        float m = (e + j < b1) ? w[j] : 0.f;
        acc[0] = fmaf(bf2f(v[j].x), m, acc[0]);
        acc[1] = fmaf(bf2f(v[j].y), m, acc[1]);
        acc[2] = fmaf(bf2f(v[j].z), m, acc[2]);
        acc[3] = fmaf(bf2f(v[j].w), m, acc[3]);
      }
    }

    const f32x4 b = *(const f32x4*)(conv_bias + lane * 4);
    acc[0] = fmaf(acc[0], di, b[0]);
    acc[1] = fmaf(acc[1], di, b[1]);
    acc[2] = fmaf(acc[2], di, b[2]);
    acc[3] = fmaf(acc[3], di, b[3]);
    __builtin_nontemporal_store(acc, (f32x4*)(out + ((size_t)row * 64 + lane) * 4));
    s1 = acc[0] + acc[1] + acc[2] + acc[3];
    s2 = acc[0] * acc[0] + acc[1] * acc[1] + acc[2] * acc[2] + acc[3] * acc[3];
  }

  __shared__ float r1[256];
  __shared__ float r2[256];
  int t = threadIdx.x;
  r1[t] = s1;
  r2[t] = s2;
  __syncthreads();
  for (int off = 128; off > 0; off >>= 1) {
    if (t < off) { r1[t] += r1[t + off]; r2[t] += r2[t + off]; }
    __syncthreads();
  }
  if (t == 0) {
    double2 pp;
    pp.x = (double)r1[0];
    pp.y = (double)r2[0];
    partials[blockIdx.x] = pp;
  }
}

// ---- 4: finalize stats ------------------------------------------------------

__global__ void finalize_stats(const double2* __restrict__ partials, int nb,
                               float* __restrict__ stats, double cnt) {
  __shared__ double q1[1024];
  __shared__ double q2[1024];
  int t = threadIdx.x;
  double a1 = 0.0, a2 = 0.0;
  for (int i = t; i < nb; i += 1024) {
    double2 pp = partials[i];
    a1 += pp.x;
    a2 += pp.y;
  }
  q1[t] = a1;
  q2[t] = a2;
  __syncthreads();
  for (int off = 512; off > 0; off >>= 1) {
    if (t < off) { q1[t] += q1[t + off]; q2[t] += q2[t + off]; }
    __syncthreads();
  }
  if (t == 0) {
    double mu = q1[0] / cnt;
    double var = q2[0] / cnt - mu * mu;
    if (var < 0) var = 0;
    double sd = sqrt(var);
    stats[0] = (float)mu;
    stats[1] = (float)(1.0 / (sd + (double)EPSV));
  }
}

// ---- 5: LayerNorm(graph) + PReLU -------------------------------------------

__global__ void norm_prelu(float* __restrict__ out, const float* __restrict__ stats,
                           const float* __restrict__ lw, const float* __restrict__ lb,
                           const float* __restrict__ pa, int n4) {
  int i = blockIdx.x * blockDim.x + threadIdx.x;
  if (i >= n4) return;
  float mu = stats[0];
  float inv = stats[1];
  float a = pa[0];
  int c4 = (i & 63) * 4;
  const f32x4 w = *(const f32x4*)(lw + c4);
  const f32x4 b = *(const f32x4*)(lb + c4);
  f32x4 v = __builtin_nontemporal_load((const f32x4*)(out + (size_t)i * 4));
  f32x4 y;
#pragma unroll
  for (int j = 0; j < 4; ++j) {
    float yv = (v[j] - mu) * inv * w[j] + b[j];
    y[j] = yv >= 0.f ? yv : a * yv;
  }
  __builtin_nontemporal_store(y, (f32x4*)(out + (size_t)i * 4));
}

// ---- launch ---------------------------------------------------------------

extern "C" void kernel_launch(void* const* d_in, const int* in_sizes, int n_in,
                              void* d_out, int out_size, void* d_ws, size_t ws_size,
                              hipStream_t stream) {
  const float* x = (const float*)d_in[0];
  const int* eidx = (const int*)d_in[1];
  const float* W = (const float*)d_in[3];
  const float* conv_bias = (const float*)d_in[4];
  const float* ln_w = (const float*)d_in[5];
  const float* ln_b = (const float*)d_in[6];
  const float* prelu_a = (const float*)d_in[7];
  float* out = (float*)d_out;

  int N = in_sizes[0] / F;
  int E = in_sizes[1] / 2;
  const int* src = eidx;
  const int* dst = eidx + E;

  int nAggBlocks = (N + 3) / 4;
  int eb = (E + 255) / 256;
  int gemmb = (N + 63) / 64;
  int NB = (N + 255) / 256;

  char* p = (char*)d_ws;
  auto carve = [&](size_t bytes) { char* r = p; p += (bytes + 255) & ~(size_t)255; return r; };
  ushort4* hb    = (ushort4*)carve((size_t)N * 64 * sizeof(ushort4));   // bf16 h (unscaled)
  unsigned short* Wb = (unsigned short*)carve((size_t)F * F * sizeof(short));
  int* deg_cnt   = (int*)carve((size_t)N * sizeof(int));
  int* csr_fixed = (int*)carve((size_t)N * SLOTS * sizeof(int));        // 25.6 MB
  double2* partials = (double2*)carve((size_t)nAggBlocks * sizeof(double2));
  float* stats   = (float*)carve(2 * sizeof(float));

  init_prep<<<NB + 256, 256, 0, stream>>>(deg_cnt, N, NB, W, Wb);
  scatter_gemm<<<eb + gemmb, 256, 0, stream>>>(src, dst, deg_cnt, csr_fixed, E, eb,
                                               x, Wb, hb, N);
  aggregate<<<nAggBlocks, 256, 0, stream>>>(hb, deg_cnt, csr_fixed, conv_bias,
                                            out, partials, N);
  finalize_stats<<<1, 1024, 0, stream>>>(partials, nAggBlocks, stats,
                                         (double)N * (double)F);
  int n4 = N * (F / 4);
  norm_prelu<<<(n4 + 255) / 256, 256, 0, stream>>>(out, stats, ln_w, ln_b, prelu_a, n4);
}

// Round 9
// 268.240 us; speedup vs baseline: 1.0831x; 1.0831x over previous
//
#include <hip/hip_runtime.h>
#include <hip/hip_bf16.h>

// GCNBlock: 8-dispatch pipeline (R9 = R3 skeleton + wide-gather aggregate).
//   1 init_prep:  zero deg_cnt ; repack W -> Wb bf16
//   2 count_gemm: count+rank edges || full GEMM (64-row LDS tiles)
//   3-5 scan chain: block_sums, scan_bsums, write_csr (R1/R3-proven monotone CSR)
//   6 fill: contention-free rank scatter
//   7 aggregate:  NEW 2 rows/wave, 32 lanes x ushort8 (16B) per row gather
//   8 norm_prelu: redundant partials reduce (R5-proven) + LN + PReLU
// Ledger: R4 f64 1-addr atomics = CAS livelock. R5 atomic-bump fill = 16-way
// contention. R6 mega-fusion = VGPR spill. R7 split-gemm + arbitrary bucket
// order = neutral/worse. R8 one-pass fixed-stride CSR = latency-serialized
// edge chain + write amplification. R1/R3 shape is the proven optimum.
// N=50000, E=800000, F=256

#define F 256
#define EPSV 1e-5f

typedef __attribute__((ext_vector_type(8))) short short8;
typedef __attribute__((ext_vector_type(8))) unsigned short ushort8v;
typedef __attribute__((ext_vector_type(4))) float f32x4;

__device__ __forceinline__ unsigned short f2bf(float f) {
  union { float f; unsigned u; } v; v.f = f;
  unsigned r = v.u + 0x7fffu + ((v.u >> 16) & 1u);  // RNE
  return (unsigned short)(r >> 16);
}

__device__ __forceinline__ float bf2f(unsigned short u) {
  union { unsigned u; float f; } v; v.u = ((unsigned)u) << 16; return v.f;
}

// ---- 1: zero deg_cnt (blocks < NB) ; prep Wb (blocks >= NB) ----------------

__global__ void init_prep(int* __restrict__ deg_cnt, int N, int NB,
                          const float* __restrict__ W, unsigned short* __restrict__ Wb) {
  if ((int)blockIdx.x < NB) {
    int i = blockIdx.x * 256 + threadIdx.x;
    if (i < N) deg_cnt[i] = 0;
    return;
  }
  int gid = (blockIdx.x - NB) * 256 + threadIdx.x;  // 65536 total
  int j = gid & 7;
  int lane = (gid >> 3) & 63;
  int kc = (gid >> 9) & 7;
  int tt = gid >> 12;
  int k = kc * 32 + (lane >> 4) * 8 + j;
  int n = tt * 16 + (lane & 15);
  Wb[gid] = f2bf(W[k * 256 + n]);
}

// ---- 2: count+rank (blocks < eb) ; gemm 64-row tiles (blocks >= eb) --------
// GEMM writes h bf16 UNSCALED (dinv applied at gather time in aggregate).

__global__ void count_gemm(const int* __restrict__ dst, int* __restrict__ deg_cnt,
                           int* __restrict__ rank, int E, int eb,
                           const float* __restrict__ x, const unsigned short* __restrict__ Wb,
                           ushort4* __restrict__ hb, int N) {
  // +8 pad: row stride 528B -> conflict-free ds_read_b128 fragments.
  __shared__ unsigned short A[64][264];  // 33792 B -> 4 blocks/CU

  if ((int)blockIdx.x < eb) {
    int e = blockIdx.x * 256 + threadIdx.x;
    if (e < E) rank[e] = atomicAdd(&deg_cnt[dst[e]], 1);
    return;
  }

  int m0 = (blockIdx.x - eb) * 64;
  int t = threadIdx.x;
  int lane = t & 63;
  int wave = t >> 6;
  int q = lane >> 4;

  // stage A: 64 rows x 256 cols fp32->bf16, coalesced
#pragma unroll
  for (int j = 0; j < 16; ++j) {
    int idx = j * 256 + t;
    int row = idx >> 6;
    int c4 = idx & 63;
    int gr = m0 + row;
    int grc = gr < N ? gr : N - 1;
    f32x4 v = __builtin_nontemporal_load((const f32x4*)(x + (size_t)grc * F + c4 * 4));
    ushort4 u;
    u.x = f2bf(v[0]); u.y = f2bf(v[1]); u.z = f2bf(v[2]); u.w = f2bf(v[3]);
    *(ushort4*)&A[row][c4 * 4] = u;
  }
  __syncthreads();

  f32x4 acc[4][4];
#pragma unroll
  for (int m = 0; m < 4; ++m)
#pragma unroll
    for (int tt = 0; tt < 4; ++tt)
      acc[m][tt] = (f32x4){0.f, 0.f, 0.f, 0.f};

  int arow = lane & 15;
  for (int kc = 0; kc < 8; ++kc) {
    short8 a[4];
#pragma unroll
    for (int m = 0; m < 4; ++m)
      a[m] = *(const short8*)&A[m * 16 + arow][kc * 32 + q * 8];
#pragma unroll
    for (int tt = 0; tt < 4; ++tt) {
      const short8 b = *(const short8*)(Wb + (((wave * 4 + tt) * 8 + kc) * 64 + lane) * 8);
#pragma unroll
      for (int m = 0; m < 4; ++m)
        acc[m][tt] = __builtin_amdgcn_mfma_f32_16x16x32_bf16(a[m], b, acc[m][tt], 0, 0, 0);
    }
  }
  __syncthreads();

  // epilogue: bf16 repack via LDS, coalesced store (h UNSCALED)
  int ccol = lane & 15;
#pragma unroll
  for (int m = 0; m < 4; ++m) {
#pragma unroll
    for (int rr = 0; rr < 4; ++rr) {
      int lrow = m * 16 + q * 4 + rr;
#pragma unroll
      for (int tt = 0; tt < 4; ++tt)
        A[lrow][(wave * 4 + tt) * 16 + ccol] = f2bf(acc[m][tt][rr]);
    }
  }
  __syncthreads();
#pragma unroll
  for (int j = 0; j < 16; ++j) {
    int idx = j * 256 + t;
    int row = idx >> 6;
    int c4 = idx & 63;
    int grow = m0 + row;
    if (grow < N) hb[(size_t)grow * 64 + c4] = *(const ushort4*)&A[row][c4 * 4];
  }
}

// ---- 3-5: parallel scan chain (monotone CSR -- preserves gather locality) --

__global__ void block_sums(const int* __restrict__ deg_cnt, int* __restrict__ bsum,
                           float* __restrict__ dinv, int N) {
  __shared__ int s[256];
  int t = threadIdx.x;
  int i = blockIdx.x * 256 + t;
  int d = (i < N) ? deg_cnt[i] : 0;
  if (i < N) dinv[i] = rsqrtf((float)(d + 1));  // +1 self loop
  s[t] = d;
  __syncthreads();
  for (int off = 128; off > 0; off >>= 1) {
    if (t < off) s[t] += s[t + off];
    __syncthreads();
  }
  if (t == 0) bsum[blockIdx.x] = s[0];
}

__global__ void scan_bsums(const int* __restrict__ bsum, int* __restrict__ boff, int nb) {
  __shared__ int s[256];
  int t = threadIdx.x;
  int v = (t < nb) ? bsum[t] : 0;
  s[t] = v;
  __syncthreads();
  for (int off = 1; off < 256; off <<= 1) {
    int x = (t >= off) ? s[t - off] : 0;
    __syncthreads();
    s[t] += x;
    __syncthreads();
  }
  if (t < nb) boff[t] = s[t] - v;  // exclusive
}

__global__ void write_csr(const int* __restrict__ deg_cnt, const int* __restrict__ boff,
                          int* __restrict__ csr_ptr, int N, int E) {
  __shared__ int s[256];
  int t = threadIdx.x;
  int i = blockIdx.x * 256 + t;
  int v = (i < N) ? deg_cnt[i] : 0;
  s[t] = v;
  __syncthreads();
  for (int off = 1; off < 256; off <<= 1) {
    int x = (t >= off) ? s[t - off] : 0;
    __syncthreads();
    s[t] += x;
    __syncthreads();
  }
  if (i < N) csr_ptr[i] = boff[blockIdx.x] + s[t] - v;
  if (i == 0) csr_ptr[N] = E;
}

// ---- 6: fill via rank (contention-free scatter) ----------------------------

__global__ void fill(const int* __restrict__ src, const int* __restrict__ dst,
                     const int* __restrict__ rank, const int* __restrict__ csr_ptr,
                     int* __restrict__ csr_src, int E) {
  int e = blockIdx.x * 256 + threadIdx.x;
  if (e < E) {
    int d = dst[e];
    csr_src[csr_ptr[d] + rank[e]] = src[e];
  }
}

// ---- 7: aggregate -- 2 rows per wave, 32 lanes x 16B (ushort8) per row -----
// hb UNSCALED; weight w[j] = dinv[src_j] (0 for pad).  Each half-wave owns one
// row; lane l covers features [l*8, l*8+8).  Per-row VMEM gather instruction
// count halved vs the 8B/lane layout (R3: 71.5us, VALUBusy 50%).

__global__ void aggregate(const ushort4* __restrict__ hb, const int* __restrict__ csr_ptr,
                          const int* __restrict__ csr_src, const float* __restrict__ dinv,
                          const float* __restrict__ conv_bias, float* __restrict__ out,
                          double2* __restrict__ partials, int N) {
  int wave = threadIdx.x >> 6;
  int lane = threadIdx.x & 63;
  int half = lane >> 5;
  int l = lane & 31;
  int row = blockIdx.x * 8 + wave * 2 + half;
  float s1 = 0.f, s2 = 0.f;
  const unsigned short* hbs = (const unsigned short*)hb;

  if (row < N) {
    float di = dinv[row];
    int b0 = csr_ptr[row], b1 = csr_ptr[row + 1];
    ushort8v sv = *(const ushort8v*)(hbs + (size_t)row * 256 + l * 8);
    float acc[8];
#pragma unroll
    for (int c = 0; c < 8; ++c) acc[c] = bf2f(sv[c]) * di;

    for (int e = b0; e < b1; e += 8) {
      int idx[8];
#pragma unroll
      for (int j = 0; j < 8; ++j) {
        int ee = e + j;
        idx[j] = csr_src[ee < b1 ? ee : b1 - 1];
      }
      ushort8v v[8];
#pragma unroll
      for (int j = 0; j < 8; ++j)
        v[j] = *(const ushort8v*)(hbs + (size_t)idx[j] * 256 + l * 8);
      float w[8];
#pragma unroll
      for (int j = 0; j < 8; ++j) w[j] = dinv[idx[j]];
#pragma unroll
      for (int j = 0; j < 8; ++j) {
        float m = (e + j < b1) ? w[j] : 0.f;
#pragma unroll
        for (int c = 0; c < 8; ++c)
          acc[c] = fmaf(bf2f(v[j][c]), m, acc[c]);
      }
    }

    const f32x4 ba = *(const f32x4*)(conv_bias + l * 8);
    const f32x4 bb = *(const f32x4*)(conv_bias + l * 8 + 4);
    f32x4 o0, o1;
#pragma unroll
    for (int c = 0; c < 4; ++c) {
      o0[c] = fmaf(acc[c], di, ba[c]);
      o1[c] = fmaf(acc[c + 4], di, bb[c]);
    }
    float* orow = out + (size_t)row * 256 + l * 8;
    __builtin_nontemporal_store(o0, (f32x4*)orow);
    __builtin_nontemporal_store(o1, (f32x4*)(orow + 4));
#pragma unroll
    for (int c = 0; c < 4; ++c) {
      s1 += o0[c] + o1[c];
      s2 += o0[c] * o0[c] + o1[c] * o1[c];
    }
  }

  __shared__ float r1[256];
  __shared__ float r2[256];
  int t = threadIdx.x;
  r1[t] = s1;
  r2[t] = s2;
  __syncthreads();
  for (int off = 128; off > 0; off >>= 1) {
    if (t < off) { r1[t] += r1[t + off]; r2[t] += r2[t + off]; }
    __syncthreads();
  }
  if (t == 0) {
    double2 pp;
    pp.x = (double)r1[0];
    pp.y = (double)r2[0];
    partials[blockIdx.x] = pp;
  }
}

// ---- 8: redundant partials reduce + LayerNorm(graph) + PReLU ---------------

__global__ void norm_prelu(float* __restrict__ out, const double2* __restrict__ partials,
                           int nb, const float* __restrict__ lw, const float* __restrict__ lb,
                           const float* __restrict__ pa, int n4, double cnt) {
  __shared__ double q1[1024];
  __shared__ double q2[1024];
  __shared__ float sstats[2];
  int t = threadIdx.x;
  double a1 = 0.0, a2 = 0.0;
  for (int i = t; i < nb; i += 1024) {
    double2 pp = partials[i];
    a1 += pp.x;
    a2 += pp.y;
  }
  q1[t] = a1;
  q2[t] = a2;
  __syncthreads();
  for (int off = 512; off > 0; off >>= 1) {
    if (t < off) { q1[t] += q1[t + off]; q2[t] += q2[t + off]; }
    __syncthreads();
  }
  if (t == 0) {
    double mu = q1[0] / cnt;
    double var = q2[0] / cnt - mu * mu;
    if (var < 0) var = 0;
    sstats[0] = (float)mu;
    sstats[1] = (float)(1.0 / (sqrt(var) + (double)EPSV));
  }
  __syncthreads();
  float mu = sstats[0];
  float inv = sstats[1];
  float a = pa[0];
  int stride = gridDim.x * 1024;
  for (int i = blockIdx.x * 1024 + t; i < n4; i += stride) {
    int c4 = (i & 63) * 4;
    const f32x4 w = *(const f32x4*)(lw + c4);
    const f32x4 b = *(const f32x4*)(lb + c4);
    f32x4 v = __builtin_nontemporal_load((const f32x4*)(out + (size_t)i * 4));
    f32x4 y;
#pragma unroll
    for (int j = 0; j < 4; ++j) {
      float yv = (v[j] - mu) * inv * w[j] + b[j];
      y[j] = yv >= 0.f ? yv : a * yv;
    }
    __builtin_nontemporal_store(y, (f32x4*)(out + (size_t)i * 4));
  }
}

// ---- launch ---------------------------------------------------------------

extern "C" void kernel_launch(void* const* d_in, const int* in_sizes, int n_in,
                              void* d_out, int out_size, void* d_ws, size_t ws_size,
                              hipStream_t stream) {
  const float* x = (const float*)d_in[0];
  const int* eidx = (const int*)d_in[1];
  const float* W = (const float*)d_in[3];
  const float* conv_bias = (const float*)d_in[4];
  const float* ln_w = (const float*)d_in[5];
  const float* ln_b = (const float*)d_in[6];
  const float* prelu_a = (const float*)d_in[7];
  float* out = (float*)d_out;

  int N = in_sizes[0] / F;
  int E = in_sizes[1] / 2;
  const int* src = eidx;
  const int* dst = eidx + E;

  int nAggBlocks = (N + 7) / 8;
  int eb = (E + 255) / 256;
  int gemmb = (N + 63) / 64;
  int NB = (N + 255) / 256;

  char* p = (char*)d_ws;
  auto carve = [&](size_t bytes) { char* r = p; p += (bytes + 255) & ~(size_t)255; return r; };
  ushort4* hb    = (ushort4*)carve((size_t)N * 64 * sizeof(ushort4));  // bf16 h (unscaled)
  unsigned short* Wb = (unsigned short*)carve((size_t)F * F * sizeof(short));
  int* deg_cnt   = (int*)carve((size_t)N * sizeof(int));
  int* rank      = (int*)carve((size_t)E * sizeof(int));
  float* dinv    = (float*)carve((size_t)N * sizeof(float));
  int* csr_ptr   = (int*)carve((size_t)(N + 1) * sizeof(int));
  int* csr_src   = (int*)carve((size_t)E * sizeof(int));
  int* bsum      = (int*)carve((size_t)NB * sizeof(int));
  int* boff      = (int*)carve((size_t)NB * sizeof(int));
  double2* partials = (double2*)carve((size_t)nAggBlocks * sizeof(double2));

  init_prep<<<NB + 256, 256, 0, stream>>>(deg_cnt, N, NB, W, Wb);
  count_gemm<<<eb + gemmb, 256, 0, stream>>>(dst, deg_cnt, rank, E, eb, x, Wb, hb, N);
  block_sums<<<NB, 256, 0, stream>>>(deg_cnt, bsum, dinv, N);
  scan_bsums<<<1, 256, 0, stream>>>(bsum, boff, NB);
  write_csr<<<NB, 256, 0, stream>>>(deg_cnt, boff, csr_ptr, N, E);
  fill<<<eb, 256, 0, stream>>>(src, dst, rank, csr_ptr, csr_src, E);
  aggregate<<<nAggBlocks, 256, 0, stream>>>(hb, csr_ptr, csr_src, dinv,
                                            conv_bias, out, partials, N);
  int n4 = N * (F / 4);
  norm_prelu<<<256, 1024, 0, stream>>>(out, partials, nAggBlocks, ln_w, ln_b, prelu_a,
                                       n4, (double)N * (double)F);
}